// Round 14
// baseline (139.836 us; speedup 1.0000x reference)
//
#include <hip/hip_runtime.h>
#include <hip/hip_bf16.h>

// B=64, T=128, D=512. gates = x @ w_ih^T per t; f-gate unused (c0=0).
// K1: r9 structure (the 98.4us best) on a VGPR diet for 3 blocks/CU:
//     per-(t, 64-col) block, 4 waves, reg-staged w (global->VGPR->cvt->LDS),
//     24 substages kh-outer (ss = kh*12 + g*4 + cg), 1KB loads, depth-2 rs,
//     2x16KB dbuf LDS, one barrier/substage. x hi/lo frags held PER K-HALF
//     (64 VGPR, reloaded once at ss=12) instead of full-K (128) ->
//     ~170 VGPR -> __launch_bounds__(256,3) -> 12 waves/CU (+50% streams).
// K2: in-place softmax(20*h), blocks XCD-affine to the t they read.

#define B_ 64
#define T_ 128
#define D_ 512

typedef float f32x4_t __attribute__((ext_vector_type(4)));
typedef __bf16 bf16x8_t __attribute__((ext_vector_type(8)));
typedef unsigned short u16x8_t __attribute__((ext_vector_type(8)));
typedef unsigned short u16x4_t __attribute__((ext_vector_type(4)));

#define SWZ(r) ((unsigned)(((r) & 7) << 4))

// Round-to-nearest split: f = hi + lo + O(2^-18 |f|).
__device__ __forceinline__ void cvt8(float4 a, float4 b, u16x8_t& hi, u16x8_t& lo) {
  float f[8] = {a.x, a.y, a.z, a.w, b.x, b.y, b.z, b.w};
#pragma unroll
  for (int j = 0; j < 8; ++j) {
    __bf16 h = (__bf16)f[j];
    hi[j] = __builtin_bit_cast(unsigned short, h);
    float r = f[j] - (float)h;
    lo[j] = __builtin_bit_cast(unsigned short, (__bf16)r);
  }
}

__device__ __forceinline__ void cvt4(float4 v, u16x4_t& hi, u16x4_t& lo) {
  float f[4] = {v.x, v.y, v.z, v.w};
#pragma unroll
  for (int j = 0; j < 4; ++j) {
    __bf16 h = (__bf16)f[j];
    hi[j] = __builtin_bit_cast(unsigned short, h);
    float r = f[j] - (float)h;
    lo[j] = __builtin_bit_cast(unsigned short, (__bf16)r);
  }
}

__device__ __forceinline__ f32x4_t mfma16(u16x8_t a, u16x8_t b, f32x4_t c) {
  return __builtin_amdgcn_mfma_f32_16x16x32_bf16(
      __builtin_bit_cast(bf16x8_t, a), __builtin_bit_cast(bf16x8_t, b), c, 0, 0, 0);
}

__device__ __forceinline__ float sigmoid_f(float v) { return 1.0f / (1.0f + __expf(-v)); }
__device__ __forceinline__ float tanh_f(float v) { return 1.0f - 2.0f / (__expf(2.0f * v) + 1.0f); }

// Grid 1024 = 128 t x 8 d-tiles. Wave wv stages w-rows wv*4..+4, computes b-rows wv*16..+16.
__global__ __launch_bounds__(256, 3) void lstm_gates_kernel(
    const float* __restrict__ x, const float* __restrict__ w, float* __restrict__ out) {
  __shared__ char lds[2][16384];  // 16 rows x 1024B (8 steps x [hi 64B | lo 64B])
  const int lane = threadIdx.x & 63;
  const int wv = threadIdx.x >> 6;
  const int bid = blockIdx.x;
  // XCD swizzle: 8 d-tiles of one t share an XCD -> x[t] L2-resident.
  const int work = (bid & 7) * 128 + (bid >> 3);
  const int t = work >> 3;
  const int d0 = (work & 7) << 6;

  const int c = lane & 15;   // frag row/col index
  const int kg = lane >> 4;  // k-subgroup 0..3

  // ---- LDS write addrs (per ISSUE: 4 rows x 1KB K-half; lane holds floats
  // [lane*4, lane*4+4) of each row's 256-float half).
  const int kl = lane * 4;
  const unsigned wst = (unsigned)(((kl >> 5) & 7) * 128);
  const unsigned wlow = (unsigned)((((kl >> 3) & 3) * 16) + ((kl & 4) << 1));
  unsigned wa_hi[4];
#pragma unroll
  for (int i = 0; i < 4; ++i) {
    const int rl = wv * 4 + i;
    wa_hi[i] = (unsigned)(rl * 1024) + wst + (wlow ^ SWZ(rl));
  }
  // Read side: col c, local k-step st (0..7), group kg; lo = hi ^ 64.
  const unsigned q_hi = ((unsigned)(kg * 16)) ^ SWZ(c);
  const unsigned rbase = (unsigned)(c * 1024);

  const int grow[3] = {0, 1024, 1536};  // gate row bases i, g(2D), o(3D); f skipped
  const char* wt = (const char*)w + ((size_t)t << 22) + (size_t)d0 * 2048;
  const float* xrow = x + (((size_t)(wv * 16 + c) * T_ + t) << 9) + kg * 8;

  f32x4_t acc[12];
#pragma unroll
  for (int s = 0; s < 12; ++s) acc[s] = (f32x4_t){0.f, 0.f, 0.f, 0.f};

  u16x8_t xh[8], xl[8];  // current K-half only (64 VGPR)
  float4 rs0[4], rs1[4];

  // x frags for K-half KH: b-row wv*16+c, k = KH*256 + st*32 + kg*8 + j.
#define LOADX(KH)                                                               \
  do {                                                                          \
    _Pragma("unroll") for (int st_ = 0; st_ < 8; ++st_) {                       \
      float4 a_ = *(const float4*)(xrow + (KH) * 256 + st_ * 32);               \
      float4 b_ = *(const float4*)(xrow + (KH) * 256 + st_ * 32 + 4);           \
      cvt8(a_, b_, xh[st_], xl[st_]);                                           \
    }                                                                           \
  } while (0)

  // substage SS = kh*12 + g*4 + cg: rows grow[g]+cg*16+wv*4..+4, K-half kh.
#define WOFF(SS)                                                                \
  ((size_t)(grow[((SS) % 12) >> 2] + (((SS) % 12) & 3) * 16 + wv * 4) * 2048 +  \
   (size_t)((SS) / 12) * 1024)

#define ISSUE(SS, RS)                                                           \
  do {                                                                          \
    const char* gb_ = wt + WOFF(SS) + lane * 16;                                \
    _Pragma("unroll") for (int i_ = 0; i_ < 4; ++i_)                            \
        RS[i_] = *(const float4*)(gb_ + (size_t)i_ * 2048);                     \
  } while (0)

#define WRITE(SS, RS)                                                           \
  do {                                                                          \
    char* lb_ = &lds[(SS) & 1][0];                                              \
    _Pragma("unroll") for (int i_ = 0; i_ < 4; ++i_) {                          \
      u16x4_t h_, l_;                                                           \
      cvt4(RS[i_], h_, l_);                                                     \
      *(u16x4_t*)(lb_ + wa_hi[i_]) = h_;                                        \
      *(u16x4_t*)(lb_ + (wa_hi[i_] ^ 64u)) = l_;                                \
    }                                                                           \
  } while (0)

#define BARRIER asm volatile("s_waitcnt lgkmcnt(0)\n\ts_barrier" ::: "memory")

#define COMPUTE(SS)                                                             \
  do {                                                                          \
    const char* lb_ = &lds[(SS) & 1][0];                                        \
    _Pragma("unroll") for (int st_ = 0; st_ < 8; ++st_) {                       \
      u16x8_t wh_ = *(const u16x8_t*)(lb_ + rbase + st_ * 128 + q_hi);          \
      u16x8_t wl_ = *(const u16x8_t*)(lb_ + rbase + st_ * 128 + (q_hi ^ 64u));  \
      acc[(SS) % 12] = mfma16(xh[st_], wh_, acc[(SS) % 12]);                    \
      acc[(SS) % 12] = mfma16(xh[st_], wl_, acc[(SS) % 12]);                    \
      acc[(SS) % 12] = mfma16(xl[st_], wh_, acc[(SS) % 12]);                    \
    }                                                                           \
  } while (0)

#define STEP(SS, RS)                        \
  WRITE(SS, RS);                            \
  if ((SS) + 2 < 24) ISSUE((SS) + 2, RS);   \
  BARRIER;                                  \
  COMPUTE(SS)

  ISSUE(0, rs0);
  ISSUE(1, rs1);

  LOADX(0);
  STEP(0, rs0);  STEP(1, rs1);  STEP(2, rs0);  STEP(3, rs1);
  STEP(4, rs0);  STEP(5, rs1);  STEP(6, rs0);  STEP(7, rs1);
  STEP(8, rs0);  STEP(9, rs1);  STEP(10, rs0); STEP(11, rs1);
  LOADX(1);
  STEP(12, rs0); STEP(13, rs1); STEP(14, rs0); STEP(15, rs1);
  STEP(16, rs0); STEP(17, rs1); STEP(18, rs0); STEP(19, rs1);
  STEP(20, rs0); STEP(21, rs1); STEP(22, rs0); STEP(23, rs1);

#undef STEP
#undef COMPUTE
#undef WRITE
#undef ISSUE
#undef WOFF
#undef LOADX

  // LSTM activation + h write. C frag: col = c, row = kg*4 + j. acc idx = g*4+cg.
#pragma unroll
  for (int cg = 0; cg < 4; ++cg) {
#pragma unroll
    for (int j = 0; j < 4; ++j) {
      float iv = acc[cg][j];
      float gv = acc[4 + cg][j];
      float ov = acc[8 + cg][j];
      float cc = sigmoid_f(iv) * tanh_f(gv);
      float h = sigmoid_f(ov) * tanh_f(cc);
      int b = wv * 16 + kg * 4 + j;
      out[(((size_t)b * T_ + t) << 9) + d0 + cg * 16 + c] = h;
    }
  }
}

// In-place softmax(20*h), one wave per (b,t) row. Blocks are XCD-affine to
// their t's K1 writer (bijective: j&7 = t>>4), so tail h-writes hit L2.
__global__ __launch_bounds__(256) void softmax_kernel(float* __restrict__ io) {
  const int lane = threadIdx.x & 63;
  const int j = blockIdx.x;
  const int v = j >> 3;
  const int t = (j & 7) * 16 + (v >> 4);
  const int b = (v & 15) * 4 + (threadIdx.x >> 6);
  float* p = io + (((size_t)b * T_ + t) << 9);
  float4 v0 = *(const float4*)(p + lane * 4);
  float4 v1 = *(const float4*)(p + 256 + lane * 4);
  float l[8] = {20.f * v0.x, 20.f * v0.y, 20.f * v0.z, 20.f * v0.w,
                20.f * v1.x, 20.f * v1.y, 20.f * v1.z, 20.f * v1.w};
  float m = l[0];
#pragma unroll
  for (int jj = 1; jj < 8; ++jj) m = fmaxf(m, l[jj]);
#pragma unroll
  for (int o = 32; o > 0; o >>= 1) m = fmaxf(m, __shfl_xor(m, o, 64));
  float e[8], s = 0.f;
#pragma unroll
  for (int jj = 0; jj < 8; ++jj) {
    e[jj] = __expf(l[jj] - m);
    s += e[jj];
  }
#pragma unroll
  for (int o = 32; o > 0; o >>= 1) s += __shfl_xor(s, o, 64);
  float inv = 1.0f / s;
  float4 o0 = {e[0] * inv, e[1] * inv, e[2] * inv, e[3] * inv};
  float4 o1 = {e[4] * inv, e[5] * inv, e[6] * inv, e[7] * inv};
  *(float4*)(p + lane * 4) = o0;
  *(float4*)(p + 256 + lane * 4) = o1;
}

extern "C" void kernel_launch(void* const* d_in, const int* in_sizes, int n_in,
                              void* d_out, int out_size, void* d_ws, size_t ws_size,
                              hipStream_t stream) {
  const float* x = (const float*)d_in[0];
  const float* w = (const float*)d_in[1];
  float* out = (float*)d_out;
  lstm_gates_kernel<<<T_ * 8, 256, 0, stream>>>(x, w, out);
  softmax_kernel<<<(B_ * T_) / 4, 256, 0, stream>>>(out);
}

// Round 15
// 99.057 us; speedup vs baseline: 1.4117x; 1.4117x over previous
//
#include <hip/hip_runtime.h>
#include <hip/hip_bf16.h>

// B=64, T=128, D=512. gates = x @ w_ih^T per t; f-gate unused (c0=0).
// K1: r9 structure (98.4us best) with SMOOTHED LOAD ISSUE: the 4 staging
//     loads of substage ss+2 are interleaved into ss's MFMA loop (one load
//     per 2 k-steps) instead of bursting between WRITE and the barrier.
//     Everything else identical to r9: per-(t,64-col) block, 4 waves,
//     reg-staged w (global->VGPR->cvt->swizzled LDS), 24 substages kh-outer,
//     1KB loads, depth-2 rs sets, 2x16KB dbuf LDS, one barrier/substage,
//     x hi/lo frags per K-half (64 VGPR), acc[12], launch_bounds(256,2).
// K2: in-place softmax(20*h).

#define B_ 64
#define T_ 128
#define D_ 512

typedef float f32x4_t __attribute__((ext_vector_type(4)));
typedef __bf16 bf16x8_t __attribute__((ext_vector_type(8)));
typedef unsigned short u16x8_t __attribute__((ext_vector_type(8)));
typedef unsigned short u16x4_t __attribute__((ext_vector_type(4)));

#define SWZ(r) ((unsigned)(((r) & 7) << 4))

// Round-to-nearest split: f = hi + lo + O(2^-18 |f|).
__device__ __forceinline__ void cvt8(float4 a, float4 b, u16x8_t& hi, u16x8_t& lo) {
  float f[8] = {a.x, a.y, a.z, a.w, b.x, b.y, b.z, b.w};
#pragma unroll
  for (int j = 0; j < 8; ++j) {
    __bf16 h = (__bf16)f[j];
    hi[j] = __builtin_bit_cast(unsigned short, h);
    float r = f[j] - (float)h;
    lo[j] = __builtin_bit_cast(unsigned short, (__bf16)r);
  }
}

__device__ __forceinline__ void cvt4(float4 v, u16x4_t& hi, u16x4_t& lo) {
  float f[4] = {v.x, v.y, v.z, v.w};
#pragma unroll
  for (int j = 0; j < 4; ++j) {
    __bf16 h = (__bf16)f[j];
    hi[j] = __builtin_bit_cast(unsigned short, h);
    float r = f[j] - (float)h;
    lo[j] = __builtin_bit_cast(unsigned short, (__bf16)r);
  }
}

__device__ __forceinline__ f32x4_t mfma16(u16x8_t a, u16x8_t b, f32x4_t c) {
  return __builtin_amdgcn_mfma_f32_16x16x32_bf16(
      __builtin_bit_cast(bf16x8_t, a), __builtin_bit_cast(bf16x8_t, b), c, 0, 0, 0);
}

__device__ __forceinline__ float sigmoid_f(float v) { return 1.0f / (1.0f + __expf(-v)); }
__device__ __forceinline__ float tanh_f(float v) { return 1.0f - 2.0f / (__expf(2.0f * v) + 1.0f); }

// Grid 1024 = 128 t x 8 d-tiles. Wave wv stages w-rows wv*4..+4, computes b-rows wv*16..+16.
__global__ __launch_bounds__(256, 2) void lstm_gates_kernel(
    const float* __restrict__ x, const float* __restrict__ w, float* __restrict__ out) {
  __shared__ char lds[2][16384];  // 16 rows x 1024B (8 steps x [hi 64B | lo 64B])
  const int lane = threadIdx.x & 63;
  const int wv = threadIdx.x >> 6;
  const int bid = blockIdx.x;
  // XCD swizzle: 8 d-tiles of one t share an XCD -> x[t] L2-resident.
  const int work = (bid & 7) * 128 + (bid >> 3);
  const int t = work >> 3;
  const int d0 = (work & 7) << 6;

  const int c = lane & 15;   // frag row/col index
  const int kg = lane >> 4;  // k-subgroup 0..3

  // ---- LDS write addrs (per ISSUE: 4 rows x 1KB K-half; lane holds floats
  // [lane*4, lane*4+4) of each row's 256-float half).
  const int kl = lane * 4;
  const unsigned wst = (unsigned)(((kl >> 5) & 7) * 128);
  const unsigned wlow = (unsigned)((((kl >> 3) & 3) * 16) + ((kl & 4) << 1));
  unsigned wa_hi[4];
#pragma unroll
  for (int i = 0; i < 4; ++i) {
    const int rl = wv * 4 + i;
    wa_hi[i] = (unsigned)(rl * 1024) + wst + (wlow ^ SWZ(rl));
  }
  // Read side: col c, local k-step st (0..7), group kg; lo = hi ^ 64.
  const unsigned q_hi = ((unsigned)(kg * 16)) ^ SWZ(c);
  const unsigned rbase = (unsigned)(c * 1024);

  const int grow[3] = {0, 1024, 1536};  // gate row bases i, g(2D), o(3D); f skipped
  const char* wt = (const char*)w + ((size_t)t << 22) + (size_t)d0 * 2048;
  const float* xrow = x + (((size_t)(wv * 16 + c) * T_ + t) << 9) + kg * 8;

  f32x4_t acc[12];
#pragma unroll
  for (int s = 0; s < 12; ++s) acc[s] = (f32x4_t){0.f, 0.f, 0.f, 0.f};

  u16x8_t xh[8], xl[8];  // current K-half only (64 VGPR)
  float4 rs0[4], rs1[4];

  // x frags for K-half KH: b-row wv*16+c, k = KH*256 + st*32 + kg*8 + j.
#define LOADX(KH)                                                               \
  do {                                                                          \
    _Pragma("unroll") for (int st_ = 0; st_ < 8; ++st_) {                       \
      float4 a_ = *(const float4*)(xrow + (KH) * 256 + st_ * 32);               \
      float4 b_ = *(const float4*)(xrow + (KH) * 256 + st_ * 32 + 4);           \
      cvt8(a_, b_, xh[st_], xl[st_]);                                           \
    }                                                                           \
  } while (0)

  // substage SS = kh*12 + g*4 + cg: rows grow[g]+cg*16+wv*4..+4, K-half kh.
#define WOFF(SS)                                                                \
  ((size_t)(grow[((SS) % 12) >> 2] + (((SS) % 12) & 3) * 16 + wv * 4) * 2048 +  \
   (size_t)((SS) / 12) * 1024)

#define ISSUE(SS, RS)                                                           \
  do {                                                                          \
    const char* gb_ = wt + WOFF(SS) + lane * 16;                                \
    _Pragma("unroll") for (int i_ = 0; i_ < 4; ++i_)                            \
        RS[i_] = *(const float4*)(gb_ + (size_t)i_ * 2048);                     \
  } while (0)

#define WRITE(SS, RS)                                                           \
  do {                                                                          \
    char* lb_ = &lds[(SS) & 1][0];                                              \
    _Pragma("unroll") for (int i_ = 0; i_ < 4; ++i_) {                          \
      u16x4_t h_, l_;                                                           \
      cvt4(RS[i_], h_, l_);                                                     \
      *(u16x4_t*)(lb_ + wa_hi[i_]) = h_;                                        \
      *(u16x4_t*)(lb_ + (wa_hi[i_] ^ 64u)) = l_;                                \
    }                                                                           \
  } while (0)

#define BARRIER asm volatile("s_waitcnt lgkmcnt(0)\n\ts_barrier" ::: "memory")

  // Compute substage SS while drip-issuing the 4 loads of SS+2 into RS
  // (one load per 2 k-steps -> near-continuous VMEM issue from the CU).
#define COMPUTE_ILV(SS, RS)                                                     \
  do {                                                                          \
    const char* lb_ = &lds[(SS) & 1][0];                                        \
    const char* gb_ = wt + WOFF((SS) + 2) + lane * 16;                          \
    _Pragma("unroll") for (int st_ = 0; st_ < 8; ++st_) {                       \
      if (((SS) + 2 < 24) && ((st_ & 1) == 0))                                  \
        RS[st_ >> 1] = *(const float4*)(gb_ + (size_t)(st_ >> 1) * 2048);       \
      u16x8_t wh_ = *(const u16x8_t*)(lb_ + rbase + st_ * 128 + q_hi);          \
      u16x8_t wl_ = *(const u16x8_t*)(lb_ + rbase + st_ * 128 + (q_hi ^ 64u));  \
      acc[(SS) % 12] = mfma16(xh[st_], wh_, acc[(SS) % 12]);                    \
      acc[(SS) % 12] = mfma16(xh[st_], wl_, acc[(SS) % 12]);                    \
      acc[(SS) % 12] = mfma16(xl[st_], wh_, acc[(SS) % 12]);                    \
    }                                                                           \
  } while (0)

  // STEP: write current tile to LDS (data-dep waits its loads), barrier,
  // then compute with next-next substage's loads drip-issued inside.
#define STEP(SS, RS)   \
  WRITE(SS, RS);       \
  BARRIER;             \
  COMPUTE_ILV(SS, RS)

  ISSUE(0, rs0);
  ISSUE(1, rs1);

  LOADX(0);
  STEP(0, rs0);  STEP(1, rs1);  STEP(2, rs0);  STEP(3, rs1);
  STEP(4, rs0);  STEP(5, rs1);  STEP(6, rs0);  STEP(7, rs1);
  STEP(8, rs0);  STEP(9, rs1);  STEP(10, rs0); STEP(11, rs1);
  LOADX(1);
  STEP(12, rs0); STEP(13, rs1); STEP(14, rs0); STEP(15, rs1);
  STEP(16, rs0); STEP(17, rs1); STEP(18, rs0); STEP(19, rs1);
  STEP(20, rs0); STEP(21, rs1); STEP(22, rs0); STEP(23, rs1);

#undef STEP
#undef COMPUTE_ILV
#undef WRITE
#undef ISSUE
#undef WOFF
#undef LOADX

  // LSTM activation + h write. C frag: col = c, row = kg*4 + j. acc idx = g*4+cg.
#pragma unroll
  for (int cg = 0; cg < 4; ++cg) {
#pragma unroll
    for (int j = 0; j < 4; ++j) {
      float iv = acc[cg][j];
      float gv = acc[4 + cg][j];
      float ov = acc[8 + cg][j];
      float cc = sigmoid_f(iv) * tanh_f(gv);
      float h = sigmoid_f(ov) * tanh_f(cc);
      int b = wv * 16 + kg * 4 + j;
      out[(((size_t)b * T_ + t) << 9) + d0 + cg * 16 + c] = h;
    }
  }
}

// One wave per (b,t) row of 512; in-place softmax(20*h).
__global__ __launch_bounds__(256) void softmax_kernel(float* __restrict__ io) {
  const int lane = threadIdx.x & 63;
  const int row = blockIdx.x * 4 + (threadIdx.x >> 6);
  float* p = io + ((size_t)row << 9);
  float4 v0 = *(const float4*)(p + lane * 4);
  float4 v1 = *(const float4*)(p + 256 + lane * 4);
  float l[8] = {20.f * v0.x, 20.f * v0.y, 20.f * v0.z, 20.f * v0.w,
                20.f * v1.x, 20.f * v1.y, 20.f * v1.z, 20.f * v1.w};
  float m = l[0];
#pragma unroll
  for (int j = 1; j < 8; ++j) m = fmaxf(m, l[j]);
#pragma unroll
  for (int o = 32; o > 0; o >>= 1) m = fmaxf(m, __shfl_xor(m, o, 64));
  float e[8], s = 0.f;
#pragma unroll
  for (int j = 0; j < 8; ++j) {
    e[j] = __expf(l[j] - m);
    s += e[j];
  }
#pragma unroll
  for (int o = 32; o > 0; o >>= 1) s += __shfl_xor(s, o, 64);
  float inv = 1.0f / s;
  float4 o0 = {e[0] * inv, e[1] * inv, e[2] * inv, e[3] * inv};
  float4 o1 = {e[4] * inv, e[5] * inv, e[6] * inv, e[7] * inv};
  *(float4*)(p + lane * 4) = o0;
  *(float4*)(p + 256 + lane * 4) = o1;
}

extern "C" void kernel_launch(void* const* d_in, const int* in_sizes, int n_in,
                              void* d_out, int out_size, void* d_ws, size_t ws_size,
                              hipStream_t stream) {
  const float* x = (const float*)d_in[0];
  const float* w = (const float*)d_in[1];
  float* out = (float*)d_out;
  lstm_gates_kernel<<<T_ * 8, 256, 0, stream>>>(x, w, out);
  softmax_kernel<<<(B_ * T_) / 4, 256, 0, stream>>>(out);
}

// Round 16
// 93.937 us; speedup vs baseline: 1.4886x; 1.0545x over previous
//
#include <hip/hip_runtime.h>
#include <hip/hip_bf16.h>

// B=64, T=128, D=512. gates = x @ w_ih^T per t; f-gate unused (c0=0).
// K1: r9 structure (98.4us best) + NON-TEMPORAL w staging loads (nt flag):
//     w is a 402MB zero-reuse stream; NT keeps the reused data (x slices,
//     h tile) resident in L2/L3 instead of being swept out.
//     Structure: per-(t,64-col) block, 4 waves, reg-staged w
//     (global->VGPR->cvt->swizzled LDS), 24 substages kh-outer, 1KB loads,
//     depth-2 rs sets, 2x16KB dbuf LDS, one barrier/substage, x hi/lo frags
//     per K-half (64 VGPR), acc[12], launch_bounds(256,2).
// K2: in-place softmax(20*h).

#define B_ 64
#define T_ 128
#define D_ 512

typedef float f32x4_t __attribute__((ext_vector_type(4)));
typedef __bf16 bf16x8_t __attribute__((ext_vector_type(8)));
typedef unsigned short u16x8_t __attribute__((ext_vector_type(8)));
typedef unsigned short u16x4_t __attribute__((ext_vector_type(4)));

#define SWZ(r) ((unsigned)(((r) & 7) << 4))

// Round-to-nearest split: f = hi + lo + O(2^-18 |f|).
__device__ __forceinline__ void cvt8(float4 a, float4 b, u16x8_t& hi, u16x8_t& lo) {
  float f[8] = {a.x, a.y, a.z, a.w, b.x, b.y, b.z, b.w};
#pragma unroll
  for (int j = 0; j < 8; ++j) {
    __bf16 h = (__bf16)f[j];
    hi[j] = __builtin_bit_cast(unsigned short, h);
    float r = f[j] - (float)h;
    lo[j] = __builtin_bit_cast(unsigned short, (__bf16)r);
  }
}

__device__ __forceinline__ void cvt4(f32x4_t v, u16x4_t& hi, u16x4_t& lo) {
#pragma unroll
  for (int j = 0; j < 4; ++j) {
    float f = v[j];
    __bf16 h = (__bf16)f;
    hi[j] = __builtin_bit_cast(unsigned short, h);
    float r = f - (float)h;
    lo[j] = __builtin_bit_cast(unsigned short, (__bf16)r);
  }
}

__device__ __forceinline__ f32x4_t mfma16(u16x8_t a, u16x8_t b, f32x4_t c) {
  return __builtin_amdgcn_mfma_f32_16x16x32_bf16(
      __builtin_bit_cast(bf16x8_t, a), __builtin_bit_cast(bf16x8_t, b), c, 0, 0, 0);
}

__device__ __forceinline__ float sigmoid_f(float v) { return 1.0f / (1.0f + __expf(-v)); }
__device__ __forceinline__ float tanh_f(float v) { return 1.0f - 2.0f / (__expf(2.0f * v) + 1.0f); }

// Grid 1024 = 128 t x 8 d-tiles. Wave wv stages w-rows wv*4..+4, computes b-rows wv*16..+16.
__global__ __launch_bounds__(256, 2) void lstm_gates_kernel(
    const float* __restrict__ x, const float* __restrict__ w, float* __restrict__ out) {
  __shared__ char lds[2][16384];  // 16 rows x 1024B (8 steps x [hi 64B | lo 64B])
  const int lane = threadIdx.x & 63;
  const int wv = threadIdx.x >> 6;
  const int bid = blockIdx.x;
  // XCD swizzle: 8 d-tiles of one t share an XCD -> x[t] L2-resident.
  const int work = (bid & 7) * 128 + (bid >> 3);
  const int t = work >> 3;
  const int d0 = (work & 7) << 6;

  const int c = lane & 15;   // frag row/col index
  const int kg = lane >> 4;  // k-subgroup 0..3

  // ---- LDS write addrs (per ISSUE: 4 rows x 1KB K-half; lane holds floats
  // [lane*4, lane*4+4) of each row's 256-float half).
  const int kl = lane * 4;
  const unsigned wst = (unsigned)(((kl >> 5) & 7) * 128);
  const unsigned wlow = (unsigned)((((kl >> 3) & 3) * 16) + ((kl & 4) << 1));
  unsigned wa_hi[4];
#pragma unroll
  for (int i = 0; i < 4; ++i) {
    const int rl = wv * 4 + i;
    wa_hi[i] = (unsigned)(rl * 1024) + wst + (wlow ^ SWZ(rl));
  }
  // Read side: col c, local k-step st (0..7), group kg; lo = hi ^ 64.
  const unsigned q_hi = ((unsigned)(kg * 16)) ^ SWZ(c);
  const unsigned rbase = (unsigned)(c * 1024);

  const int grow[3] = {0, 1024, 1536};  // gate row bases i, g(2D), o(3D); f skipped
  const char* wt = (const char*)w + ((size_t)t << 22) + (size_t)d0 * 2048;
  const float* xrow = x + (((size_t)(wv * 16 + c) * T_ + t) << 9) + kg * 8;

  f32x4_t acc[12];
#pragma unroll
  for (int s = 0; s < 12; ++s) acc[s] = (f32x4_t){0.f, 0.f, 0.f, 0.f};

  u16x8_t xh[8], xl[8];  // current K-half only (64 VGPR)
  f32x4_t rs0[4], rs1[4];

  // x frags for K-half KH: b-row wv*16+c, k = KH*256 + st*32 + kg*8 + j.
#define LOADX(KH)                                                               \
  do {                                                                          \
    _Pragma("unroll") for (int st_ = 0; st_ < 8; ++st_) {                       \
      float4 a_ = *(const float4*)(xrow + (KH) * 256 + st_ * 32);               \
      float4 b_ = *(const float4*)(xrow + (KH) * 256 + st_ * 32 + 4);           \
      cvt8(a_, b_, xh[st_], xl[st_]);                                           \
    }                                                                           \
  } while (0)

  // substage SS = kh*12 + g*4 + cg: rows grow[g]+cg*16+wv*4..+4, K-half kh.
#define WOFF(SS)                                                                \
  ((size_t)(grow[((SS) % 12) >> 2] + (((SS) % 12) & 3) * 16 + wv * 4) * 2048 +  \
   (size_t)((SS) / 12) * 1024)

  // NON-TEMPORAL: w is zero-reuse; don't let it sweep L2/L3.
#define ISSUE(SS, RS)                                                           \
  do {                                                                          \
    const char* gb_ = wt + WOFF(SS) + lane * 16;                                \
    _Pragma("unroll") for (int i_ = 0; i_ < 4; ++i_)                            \
        RS[i_] = __builtin_nontemporal_load(                                    \
            (const f32x4_t*)(gb_ + (size_t)i_ * 2048));                         \
  } while (0)

#define WRITE(SS, RS)                                                           \
  do {                                                                          \
    char* lb_ = &lds[(SS) & 1][0];                                              \
    _Pragma("unroll") for (int i_ = 0; i_ < 4; ++i_) {                          \
      u16x4_t h_, l_;                                                           \
      cvt4(RS[i_], h_, l_);                                                     \
      *(u16x4_t*)(lb_ + wa_hi[i_]) = h_;                                        \
      *(u16x4_t*)(lb_ + (wa_hi[i_] ^ 64u)) = l_;                                \
    }                                                                           \
  } while (0)

#define BARRIER asm volatile("s_waitcnt lgkmcnt(0)\n\ts_barrier" ::: "memory")

#define COMPUTE(SS)                                                             \
  do {                                                                          \
    const char* lb_ = &lds[(SS) & 1][0];                                        \
    _Pragma("unroll") for (int st_ = 0; st_ < 8; ++st_) {                       \
      u16x8_t wh_ = *(const u16x8_t*)(lb_ + rbase + st_ * 128 + q_hi);          \
      u16x8_t wl_ = *(const u16x8_t*)(lb_ + rbase + st_ * 128 + (q_hi ^ 64u));  \
      acc[(SS) % 12] = mfma16(xh[st_], wh_, acc[(SS) % 12]);                    \
      acc[(SS) % 12] = mfma16(xh[st_], wl_, acc[(SS) % 12]);                    \
      acc[(SS) % 12] = mfma16(xl[st_], wh_, acc[(SS) % 12]);                    \
    }                                                                           \
  } while (0)

#define STEP(SS, RS)                        \
  WRITE(SS, RS);                            \
  if ((SS) + 2 < 24) ISSUE((SS) + 2, RS);   \
  BARRIER;                                  \
  COMPUTE(SS)

  ISSUE(0, rs0);
  ISSUE(1, rs1);

  LOADX(0);
  STEP(0, rs0);  STEP(1, rs1);  STEP(2, rs0);  STEP(3, rs1);
  STEP(4, rs0);  STEP(5, rs1);  STEP(6, rs0);  STEP(7, rs1);
  STEP(8, rs0);  STEP(9, rs1);  STEP(10, rs0); STEP(11, rs1);
  LOADX(1);
  STEP(12, rs0); STEP(13, rs1); STEP(14, rs0); STEP(15, rs1);
  STEP(16, rs0); STEP(17, rs1); STEP(18, rs0); STEP(19, rs1);
  STEP(20, rs0); STEP(21, rs1); STEP(22, rs0); STEP(23, rs1);

#undef STEP
#undef COMPUTE
#undef WRITE
#undef ISSUE
#undef WOFF
#undef LOADX

  // LSTM activation + h write. C frag: col = c, row = kg*4 + j. acc idx = g*4+cg.
#pragma unroll
  for (int cg = 0; cg < 4; ++cg) {
#pragma unroll
    for (int j = 0; j < 4; ++j) {
      float iv = acc[cg][j];
      float gv = acc[4 + cg][j];
      float ov = acc[8 + cg][j];
      float cc = sigmoid_f(iv) * tanh_f(gv);
      float h = sigmoid_f(ov) * tanh_f(cc);
      int b = wv * 16 + kg * 4 + j;
      out[(((size_t)b * T_ + t) << 9) + d0 + cg * 16 + c] = h;
    }
  }
}

// One wave per (b,t) row of 512; in-place softmax(20*h).
__global__ __launch_bounds__(256) void softmax_kernel(float* __restrict__ io) {
  const int lane = threadIdx.x & 63;
  const int row = blockIdx.x * 4 + (threadIdx.x >> 6);
  float* p = io + ((size_t)row << 9);
  float4 v0 = *(const float4*)(p + lane * 4);
  float4 v1 = *(const float4*)(p + 256 + lane * 4);
  float l[8] = {20.f * v0.x, 20.f * v0.y, 20.f * v0.z, 20.f * v0.w,
                20.f * v1.x, 20.f * v1.y, 20.f * v1.z, 20.f * v1.w};
  float m = l[0];
#pragma unroll
  for (int j = 1; j < 8; ++j) m = fmaxf(m, l[j]);
#pragma unroll
  for (int o = 32; o > 0; o >>= 1) m = fmaxf(m, __shfl_xor(m, o, 64));
  float e[8], s = 0.f;
#pragma unroll
  for (int j = 0; j < 8; ++j) {
    e[j] = __expf(l[j] - m);
    s += e[j];
  }
#pragma unroll
  for (int o = 32; o > 0; o >>= 1) s += __shfl_xor(s, o, 64);
  float inv = 1.0f / s;
  float4 o0 = {e[0] * inv, e[1] * inv, e[2] * inv, e[3] * inv};
  float4 o1 = {e[4] * inv, e[5] * inv, e[6] * inv, e[7] * inv};
  *(float4*)(p + lane * 4) = o0;
  *(float4*)(p + 256 + lane * 4) = o1;
}

extern "C" void kernel_launch(void* const* d_in, const int* in_sizes, int n_in,
                              void* d_out, int out_size, void* d_ws, size_t ws_size,
                              hipStream_t stream) {
  const float* x = (const float*)d_in[0];
  const float* w = (const float*)d_in[1];
  float* out = (float*)d_out;
  lstm_gates_kernel<<<T_ * 8, 256, 0, stream>>>(x, w, out);
  softmax_kernel<<<(B_ * T_) / 4, 256, 0, stream>>>(out);
}

// Round 17
// 93.117 us; speedup vs baseline: 1.5017x; 1.0088x over previous
//
#include <hip/hip_runtime.h>
#include <hip/hip_bf16.h>

// B=64, T=128, D=512. gates = x @ w_ih^T per t; f-gate unused (c0=0).
// K1: r16 (93.9us): per-(t,64-col) block, 4 waves, reg-staged w with
//     NON-TEMPORAL loads (402MB zero-reuse stream stays out of L2/L3),
//     global->VGPR->cvt->swizzled LDS, 24 substages kh-outer, 1KB loads,
//     depth-2 rs sets, 2x16KB dbuf LDS, one barrier/substage, x hi/lo frags
//     per K-half (64 VGPR), acc[12], launch_bounds(256,2). UNCHANGED.
// K2: in-place softmax(20*h); blocks XCD-AFFINE to the t-range K1 wrote on
//     that XCD (reads become same-XCD L2 hits) + NT final store.

#define B_ 64
#define T_ 128
#define D_ 512

typedef float f32x4_t __attribute__((ext_vector_type(4)));
typedef __bf16 bf16x8_t __attribute__((ext_vector_type(8)));
typedef unsigned short u16x8_t __attribute__((ext_vector_type(8)));
typedef unsigned short u16x4_t __attribute__((ext_vector_type(4)));

#define SWZ(r) ((unsigned)(((r) & 7) << 4))

// Round-to-nearest split: f = hi + lo + O(2^-18 |f|).
__device__ __forceinline__ void cvt8(float4 a, float4 b, u16x8_t& hi, u16x8_t& lo) {
  float f[8] = {a.x, a.y, a.z, a.w, b.x, b.y, b.z, b.w};
#pragma unroll
  for (int j = 0; j < 8; ++j) {
    __bf16 h = (__bf16)f[j];
    hi[j] = __builtin_bit_cast(unsigned short, h);
    float r = f[j] - (float)h;
    lo[j] = __builtin_bit_cast(unsigned short, (__bf16)r);
  }
}

__device__ __forceinline__ void cvt4(f32x4_t v, u16x4_t& hi, u16x4_t& lo) {
#pragma unroll
  for (int j = 0; j < 4; ++j) {
    float f = v[j];
    __bf16 h = (__bf16)f;
    hi[j] = __builtin_bit_cast(unsigned short, h);
    float r = f - (float)h;
    lo[j] = __builtin_bit_cast(unsigned short, (__bf16)r);
  }
}

__device__ __forceinline__ f32x4_t mfma16(u16x8_t a, u16x8_t b, f32x4_t c) {
  return __builtin_amdgcn_mfma_f32_16x16x32_bf16(
      __builtin_bit_cast(bf16x8_t, a), __builtin_bit_cast(bf16x8_t, b), c, 0, 0, 0);
}

__device__ __forceinline__ float sigmoid_f(float v) { return 1.0f / (1.0f + __expf(-v)); }
__device__ __forceinline__ float tanh_f(float v) { return 1.0f - 2.0f / (__expf(2.0f * v) + 1.0f); }

// Grid 1024 = 128 t x 8 d-tiles. Wave wv stages w-rows wv*4..+4, computes b-rows wv*16..+16.
__global__ __launch_bounds__(256, 2) void lstm_gates_kernel(
    const float* __restrict__ x, const float* __restrict__ w, float* __restrict__ out) {
  __shared__ char lds[2][16384];  // 16 rows x 1024B (8 steps x [hi 64B | lo 64B])
  const int lane = threadIdx.x & 63;
  const int wv = threadIdx.x >> 6;
  const int bid = blockIdx.x;
  // XCD swizzle: 8 d-tiles of one t share an XCD (t's tile on XCD t>>4).
  const int work = (bid & 7) * 128 + (bid >> 3);
  const int t = work >> 3;
  const int d0 = (work & 7) << 6;

  const int c = lane & 15;   // frag row/col index
  const int kg = lane >> 4;  // k-subgroup 0..3

  // ---- LDS write addrs (per ISSUE: 4 rows x 1KB K-half; lane holds floats
  // [lane*4, lane*4+4) of each row's 256-float half).
  const int kl = lane * 4;
  const unsigned wst = (unsigned)(((kl >> 5) & 7) * 128);
  const unsigned wlow = (unsigned)((((kl >> 3) & 3) * 16) + ((kl & 4) << 1));
  unsigned wa_hi[4];
#pragma unroll
  for (int i = 0; i < 4; ++i) {
    const int rl = wv * 4 + i;
    wa_hi[i] = (unsigned)(rl * 1024) + wst + (wlow ^ SWZ(rl));
  }
  // Read side: col c, local k-step st (0..7), group kg; lo = hi ^ 64.
  const unsigned q_hi = ((unsigned)(kg * 16)) ^ SWZ(c);
  const unsigned rbase = (unsigned)(c * 1024);

  const int grow[3] = {0, 1024, 1536};  // gate row bases i, g(2D), o(3D); f skipped
  const char* wt = (const char*)w + ((size_t)t << 22) + (size_t)d0 * 2048;
  const float* xrow = x + (((size_t)(wv * 16 + c) * T_ + t) << 9) + kg * 8;

  f32x4_t acc[12];
#pragma unroll
  for (int s = 0; s < 12; ++s) acc[s] = (f32x4_t){0.f, 0.f, 0.f, 0.f};

  u16x8_t xh[8], xl[8];  // current K-half only (64 VGPR)
  f32x4_t rs0[4], rs1[4];

  // x frags for K-half KH: b-row wv*16+c, k = KH*256 + st*32 + kg*8 + j.
#define LOADX(KH)                                                               \
  do {                                                                          \
    _Pragma("unroll") for (int st_ = 0; st_ < 8; ++st_) {                       \
      float4 a_ = *(const float4*)(xrow + (KH) * 256 + st_ * 32);               \
      float4 b_ = *(const float4*)(xrow + (KH) * 256 + st_ * 32 + 4);           \
      cvt8(a_, b_, xh[st_], xl[st_]);                                           \
    }                                                                           \
  } while (0)

  // substage SS = kh*12 + g*4 + cg: rows grow[g]+cg*16+wv*4..+4, K-half kh.
#define WOFF(SS)                                                                \
  ((size_t)(grow[((SS) % 12) >> 2] + (((SS) % 12) & 3) * 16 + wv * 4) * 2048 +  \
   (size_t)((SS) / 12) * 1024)

  // NON-TEMPORAL: w is zero-reuse; don't let it sweep L2/L3.
#define ISSUE(SS, RS)                                                           \
  do {                                                                          \
    const char* gb_ = wt + WOFF(SS) + lane * 16;                                \
    _Pragma("unroll") for (int i_ = 0; i_ < 4; ++i_)                            \
        RS[i_] = __builtin_nontemporal_load(                                    \
            (const f32x4_t*)(gb_ + (size_t)i_ * 2048));                         \
  } while (0)

#define WRITE(SS, RS)                                                           \
  do {                                                                          \
    char* lb_ = &lds[(SS) & 1][0];                                              \
    _Pragma("unroll") for (int i_ = 0; i_ < 4; ++i_) {                          \
      u16x4_t h_, l_;                                                           \
      cvt4(RS[i_], h_, l_);                                                     \
      *(u16x4_t*)(lb_ + wa_hi[i_]) = h_;                                        \
      *(u16x4_t*)(lb_ + (wa_hi[i_] ^ 64u)) = l_;                                \
    }                                                                           \
  } while (0)

#define BARRIER asm volatile("s_waitcnt lgkmcnt(0)\n\ts_barrier" ::: "memory")

#define COMPUTE(SS)                                                             \
  do {                                                                          \
    const char* lb_ = &lds[(SS) & 1][0];                                        \
    _Pragma("unroll") for (int st_ = 0; st_ < 8; ++st_) {                       \
      u16x8_t wh_ = *(const u16x8_t*)(lb_ + rbase + st_ * 128 + q_hi);          \
      u16x8_t wl_ = *(const u16x8_t*)(lb_ + rbase + st_ * 128 + (q_hi ^ 64u));  \
      acc[(SS) % 12] = mfma16(xh[st_], wh_, acc[(SS) % 12]);                    \
      acc[(SS) % 12] = mfma16(xh[st_], wl_, acc[(SS) % 12]);                    \
      acc[(SS) % 12] = mfma16(xl[st_], wh_, acc[(SS) % 12]);                    \
    }                                                                           \
  } while (0)

#define STEP(SS, RS)                        \
  WRITE(SS, RS);                            \
  if ((SS) + 2 < 24) ISSUE((SS) + 2, RS);   \
  BARRIER;                                  \
  COMPUTE(SS)

  ISSUE(0, rs0);
  ISSUE(1, rs1);

  LOADX(0);
  STEP(0, rs0);  STEP(1, rs1);  STEP(2, rs0);  STEP(3, rs1);
  STEP(4, rs0);  STEP(5, rs1);  STEP(6, rs0);  STEP(7, rs1);
  STEP(8, rs0);  STEP(9, rs1);  STEP(10, rs0); STEP(11, rs1);
  LOADX(1);
  STEP(12, rs0); STEP(13, rs1); STEP(14, rs0); STEP(15, rs1);
  STEP(16, rs0); STEP(17, rs1); STEP(18, rs0); STEP(19, rs1);
  STEP(20, rs0); STEP(21, rs1); STEP(22, rs0); STEP(23, rs1);

#undef STEP
#undef COMPUTE
#undef WRITE
#undef ISSUE
#undef WOFF
#undef LOADX

  // LSTM activation + h write. C frag: col = c, row = kg*4 + j. acc idx = g*4+cg.
#pragma unroll
  for (int cg = 0; cg < 4; ++cg) {
#pragma unroll
    for (int j = 0; j < 4; ++j) {
      float iv = acc[cg][j];
      float gv = acc[4 + cg][j];
      float ov = acc[8 + cg][j];
      float cc = sigmoid_f(iv) * tanh_f(gv);
      float h = sigmoid_f(ov) * tanh_f(cc);
      int b = wv * 16 + kg * 4 + j;
      out[(((size_t)b * T_ + t) << 9) + d0 + cg * 16 + c] = h;
    }
  }
}

// In-place softmax(20*h). Grid 2048, 4 waves = 4 rows/block. XCD-affine:
// block j (on XCD j&7) handles only t in [(j&7)*16, +16) - the t-range whose
// h-tile K1 wrote on that XCD's L2. Final store is non-temporal (never re-read).
__global__ __launch_bounds__(256) void softmax_kernel(float* __restrict__ io) {
  const int lane = threadIdx.x & 63;
  const int wv = threadIdx.x >> 6;
  const int j = blockIdx.x;
  const int xcd = j & 7;
  const int v = j >> 3;                      // 0..255
  const int b = v >> 2;                      // 0..63
  const int t = xcd * 16 + (v & 3) * 4 + wv; // 0..127, XCD-affine
  float* p = io + (((size_t)b * T_ + t) << 9);
  float4 v0 = *(const float4*)(p + lane * 4);
  float4 v1 = *(const float4*)(p + 256 + lane * 4);
  float l[8] = {20.f * v0.x, 20.f * v0.y, 20.f * v0.z, 20.f * v0.w,
                20.f * v1.x, 20.f * v1.y, 20.f * v1.z, 20.f * v1.w};
  float m = l[0];
#pragma unroll
  for (int jj = 1; jj < 8; ++jj) m = fmaxf(m, l[jj]);
#pragma unroll
  for (int o = 32; o > 0; o >>= 1) m = fmaxf(m, __shfl_xor(m, o, 64));
  float e[8], s = 0.f;
#pragma unroll
  for (int jj = 0; jj < 8; ++jj) {
    e[jj] = __expf(l[jj] - m);
    s += e[jj];
  }
#pragma unroll
  for (int o = 32; o > 0; o >>= 1) s += __shfl_xor(s, o, 64);
  float inv = 1.0f / s;
  f32x4_t o0 = {e[0] * inv, e[1] * inv, e[2] * inv, e[3] * inv};
  f32x4_t o1 = {e[4] * inv, e[5] * inv, e[6] * inv, e[7] * inv};
  __builtin_nontemporal_store(o0, (f32x4_t*)(p + lane * 4));
  __builtin_nontemporal_store(o1, (f32x4_t*)(p + 256 + lane * 4));
}

extern "C" void kernel_launch(void* const* d_in, const int* in_sizes, int n_in,
                              void* d_out, int out_size, void* d_ws, size_t ws_size,
                              hipStream_t stream) {
  const float* x = (const float*)d_in[0];
  const float* w = (const float*)d_in[1];
  float* out = (float*)d_out;
  lstm_gates_kernel<<<T_ * 8, 256, 0, stream>>>(x, w, out);
  softmax_kernel<<<(B_ * T_) / 4, 256, 0, stream>>>(out);
}